// Round 6
// baseline (453.496 us; speedup 1.0000x reference)
//
#include <hip/hip_runtime.h>
#include <hip/hip_bf16.h>
#include <math.h>

typedef __bf16 bf16x8 __attribute__((ext_vector_type(8)));
typedef float f32x4 __attribute__((ext_vector_type(4)));
typedef float f32x16 __attribute__((ext_vector_type(16)));
typedef unsigned short ushort8_t __attribute__((ext_vector_type(8)));
typedef unsigned short ushort4_t __attribute__((ext_vector_type(4)));

#define DIMSZ 2048
#define NHEADS 16
#define HD 128
#define INNER 2048
#define T_SEQ 2048
#define BATCH 2
#define BT_ROWS (BATCH * T_SEQ)      // 4096
#define QKV_COLS (3 * INNER)         // 6144

__device__ __forceinline__ float bf2f(unsigned short u) {
  union { unsigned int ui; float f; } v; v.ui = ((unsigned int)u) << 16; return v.f;
}
__device__ __forceinline__ unsigned short f2bf(float f) {
  union { float f; unsigned int ui; } v; v.f = f;
  unsigned int u = v.ui;
  return (unsigned short)((u + 0x7FFFu + ((u >> 16) & 1u)) >> 16);  // RNE
}
__device__ __forceinline__ bf16x8 ld8(const unsigned short* p) {
  return *(const bf16x8*)p;
}
// async global->LDS, 16B/lane. LDS dest = wave-uniform base + lane*16.
__device__ __forceinline__ void gl16(const unsigned short* g, unsigned short* l) {
  __builtin_amdgcn_global_load_lds(
      (const __attribute__((address_space(1))) unsigned int*)g,
      (__attribute__((address_space(3))) unsigned int*)l, 16, 0, 0);
}

// -------- dtype probe --------
__global__ void detect_dtype(const unsigned short* __restrict__ w, int* __restrict__ flag) {
  __shared__ int sh;
  if (threadIdx.x == 0) sh = 0;
  __syncthreads();
  int hit = 0;
  for (int i = threadIdx.x; i < 8192; i += 256) {
    unsigned int e = (w[i] >> 7) & 0xFF;
    if (e >= 0x7F) hit = 1;                       // |v| >= 1.0 impossible for bf16 weights
  }
  if (hit) atomicOr(&sh, 1);
  __syncthreads();
  if (threadIdx.x == 0) *flag = sh;               // 1 => inputs are fp32
}

// -------- x convert: fp32 (or bf16 passthrough) -> bf16 --------
__global__ void convert_x(const void* __restrict__ in, unsigned short* __restrict__ out,
                          const int* __restrict__ flag) {
  const bool f32 = (*flag != 0);
  size_t i = ((size_t)blockIdx.x * 256 + threadIdx.x) * 8;
  if (f32) {
    const float* inf = (const float*)in;
    float4 u0 = *(const float4*)&inf[i];
    float4 u1 = *(const float4*)&inf[i + 4];
    ushort8_t t;
    t[0] = f2bf(u0.x); t[1] = f2bf(u0.y); t[2] = f2bf(u0.z); t[3] = f2bf(u0.w);
    t[4] = f2bf(u1.x); t[5] = f2bf(u1.y); t[6] = f2bf(u1.z); t[7] = f2bf(u1.w);
    *(ushort8_t*)&out[i] = t;
  } else {
    *(uint4*)&out[i] = *(const uint4*)&((const unsigned short*)in)[i];
  }
}

// -------- weight transpose (+ optional fp32->bf16) --------
__global__ void transpose_any(const void* __restrict__ in, unsigned short* __restrict__ out,
                              int R, int C, const int* __restrict__ flag) {
  const bool f32 = (*flag != 0);
  __shared__ unsigned short tile[32][33];
  int c0 = blockIdx.x * 32, r0 = blockIdx.y * 32;
  int tx = threadIdx.x & 31, ty = threadIdx.x >> 5;
  if (f32) {
    const float* inf = (const float*)in;
    #pragma unroll
    for (int i = 0; i < 4; ++i)
      tile[ty + i * 8][tx] = f2bf(inf[(size_t)(r0 + ty + i * 8) * C + c0 + tx]);
  } else {
    const unsigned short* inu = (const unsigned short*)in;
    #pragma unroll
    for (int i = 0; i < 4; ++i)
      tile[ty + i * 8][tx] = inu[(size_t)(r0 + ty + i * 8) * C + c0 + tx];
  }
  __syncthreads();
  #pragma unroll
  for (int i = 0; i < 4; ++i)
    out[(size_t)(c0 + ty + i * 8) * R + r0 + tx] = tile[tx][ty + i * 8];
}

// -------- rope tables: cos/sin [2048][64] fp32 --------
__global__ void rope_tables(float* __restrict__ ct, float* __restrict__ st) {
  int i = blockIdx.x * 256 + threadIdx.x;     // 131072
  int t = i >> 6, j = i & 63;
  float inv_freq = exp2f(-(float)j * 0.20762050593046017f);  // log2(10000)/64
  float ang = (float)t * inv_freq;
  ct[i] = cosf(ang);
  st[i] = sinf(ang);
}

// ------------- GEMM v2: BK=64, XOR-swizzled LDS segments, optional fused RoPE epilogue -------------
// C[M][N] = A[M][K]*Bt[N][K]^T. 128x128 tile, 4 waves, 16x16x32 MFMA.
// LDS layout: tile[r][s_phys] holds global segment s_phys ^ (r&7)  (8-elem segs, 8 per row).
#define GBK 64
__global__ __launch_bounds__(256) void gemm_lds2(const unsigned short* __restrict__ A,
                                                 const unsigned short* __restrict__ Bt,
                                                 unsigned short* __restrict__ Cb,
                                                 float* __restrict__ Cf,
                                                 int M, int N, int K,
                                                 const float* __restrict__ costab,
                                                 const float* __restrict__ sintab,
                                                 int rope_limit) {
  __shared__ union {
    unsigned short stage[2][128 * GBK];   // As, Bs (16 KB each)
    unsigned short tile[128 * 136];       // rope epilogue staging (34816 B)
  } sm;
  unsigned short* As = sm.stage[0];
  unsigned short* Bs = sm.stage[1];
  const int tid = threadIdx.x;
  const int m0 = blockIdx.y * 128, n0 = blockIdx.x * 128;
  const int w = tid >> 6, L = tid & 63, c = L & 15, quad = L >> 4;
  const int wm = (w & 1) * 64, wn = (w >> 1) * 64;
  f32x4 acc[4][4];
  #pragma unroll
  for (int i = 0; i < 4; ++i)
    #pragma unroll
    for (int j = 0; j < 4; ++j) acc[i][j] = (f32x4)0.0f;

  for (int k0 = 0; k0 < K; k0 += GBK) {
    #pragma unroll
    for (int p = 0; p < 4; ++p) {
      int ci = p * 256 + w * 64 + L;      // slot 0..1023
      int r = ci >> 3, s = ci & 7;
      int sl = s ^ (r & 7);               // swizzle via global source permutation
      gl16(&A[(size_t)(m0 + r) * K + k0 + sl * 8], &As[(p * 256 + w * 64) * 8]);
      gl16(&Bt[(size_t)(n0 + r) * K + k0 + sl * 8], &Bs[(p * 256 + w * 64) * 8]);
    }
    __syncthreads();
    #pragma unroll
    for (int sub = 0; sub < 2; ++sub) {
      bf16x8 af[4], bfr[4];
      #pragma unroll
      for (int i = 0; i < 4; ++i)
        af[i] = ld8(&As[(wm + i * 16 + c) * GBK + (((sub * 4 + quad) ^ (c & 7)) * 8)]);
      #pragma unroll
      for (int j = 0; j < 4; ++j)
        bfr[j] = ld8(&Bs[(wn + j * 16 + c) * GBK + (((sub * 4 + quad) ^ (c & 7)) * 8)]);
      #pragma unroll
      for (int i = 0; i < 4; ++i)
        #pragma unroll
        for (int j = 0; j < 4; ++j)
          acc[i][j] = __builtin_amdgcn_mfma_f32_16x16x32_bf16(af[i], bfr[j], acc[i][j], 0, 0, 0);
    }
    __syncthreads();
  }
  // C/D layout: col = lane&15, row = quad*4 + reg
  if (Cf) {
    #pragma unroll
    for (int i = 0; i < 4; ++i)
      #pragma unroll
      for (int j = 0; j < 4; ++j)
        #pragma unroll
        for (int r = 0; r < 4; ++r)
          Cf[(size_t)(m0 + wm + i * 16 + quad * 4 + r) * N + n0 + wn + j * 16 + c] = acc[i][j][r];
  } else if (n0 < rope_limit) {
    // fused RoPE: this block covers one head's 128 dims of q or k.
    #pragma unroll
    for (int i = 0; i < 4; ++i)
      #pragma unroll
      for (int j = 0; j < 4; ++j)
        #pragma unroll
        for (int r = 0; r < 4; ++r)
          sm.tile[(wm + i * 16 + quad * 4 + r) * 136 + wn + j * 16 + c] = f2bf(acc[i][j][r]);
    __syncthreads();
    int rbase = w * 8 + (L >> 3);          // 0..31
    int cb = (L & 7) * 8;                  // 0..56
    #pragma unroll
    for (int p = 0; p < 4; ++p) {
      int row = rbase + p * 32;
      int tp = (m0 + row) & (T_SEQ - 1);
      const float* cr = &costab[tp * 64 + cb];
      const float* sr = &sintab[tp * 64 + cb];
      float4 c0v = *(const float4*)cr, c1v = *(const float4*)(cr + 4);
      float4 s0v = *(const float4*)sr, s1v = *(const float4*)(sr + 4);
      float cv[8] = {c0v.x, c0v.y, c0v.z, c0v.w, c1v.x, c1v.y, c1v.z, c1v.w};
      float sv[8] = {s0v.x, s0v.y, s0v.z, s0v.w, s1v.x, s1v.y, s1v.z, s1v.w};
      bf16x8 x1 = ld8(&sm.tile[row * 136 + cb]);
      bf16x8 x2 = ld8(&sm.tile[row * 136 + cb + 64]);
      ushort8_t o1, o2;
      #pragma unroll
      for (int e = 0; e < 8; ++e) {
        float a = (float)x1[e], bq = (float)x2[e];
        o1[e] = f2bf(a * cv[e] - bq * sv[e]);
        o2[e] = f2bf(bq * cv[e] + a * sv[e]);
      }
      *(ushort8_t*)&Cb[(size_t)(m0 + row) * N + n0 + cb] = o1;
      *(ushort8_t*)&Cb[(size_t)(m0 + row) * N + n0 + cb + 64] = o2;
    }
    __syncthreads();   // tile reuse safe if loop ever re-entered (it isn't) / uniform exit
  } else {
    #pragma unroll
    for (int i = 0; i < 4; ++i)
      #pragma unroll
      for (int j = 0; j < 4; ++j)
        #pragma unroll
        for (int r = 0; r < 4; ++r)
          Cb[(size_t)(m0 + wm + i * 16 + quad * 4 + r) * N + n0 + wn + j * 16 + c] =
              f2bf(acc[i][j][r]);
  }
}

// ---------------- causal flash attention v4: 32x32x16 MFMA, S^T trick, reg-prefetch pipeline ----------------
#define KT3 64
#define KSTR3 136
#define VSTR3 72
#define PSTR3 68
#define SM_VS (64 * KSTR3 * 2)             // 17408
#define SM_PS (SM_VS + 128 * VSTR3 * 2)    // 35840
#define SM_LR (SM_PS + 64 * PSTR3 * 2)     // 44544
#define SM_TOT (SM_LR + 2 * 64 * 4)        // 45056
__global__ __launch_bounds__(256, 2) void flash_attn4(const unsigned short* __restrict__ qkv,
                                                      unsigned short* __restrict__ aout) {
  __shared__ char smem[SM_TOT];
  unsigned short* Ks = (unsigned short*)smem;              // [64 key][KSTR3]
  unsigned short* Vs = (unsigned short*)(smem + SM_VS);    // [128 d][VSTR3] (transposed)
  unsigned short* Ps = (unsigned short*)(smem + SM_PS);    // [64 q][PSTR3]
  float* lred = (float*)(smem + SM_LR);                    // [2 wk][64 q]
  float* Os = (float*)smem;                                // overlay: [2 wq][64 lane][68]

  const int tid = threadIdx.x, wave = tid >> 6, lane = tid & 63;
  const int wq = wave & 1, wk = wave >> 1;
  const int l31 = lane & 31, lh = lane >> 5;
  const int bh = blockIdx.y, b = bh >> 4, h = bh & 15;
  const unsigned short* qbase = qkv + (size_t)b * T_SEQ * QKV_COLS + h * HD;
  const unsigned short* kbase = qbase + INNER;
  const unsigned short* vbase = qbase + 2 * INNER;
  const float cf = 0.12751743f;            // (1/sqrt(128)) * log2(e)
  const int rp = tid & 31, seg = tid >> 5;

  uint4 kreg[4];
  ushort8_t v0a, v0b, v1a, v1b;
  auto loadKV = [&](int kt) {
    #pragma unroll
    for (int p = 0; p < 4; ++p) {
      int ci = p * 256 + tid, r = ci >> 4, s = ci & 15;
      kreg[p] = *(const uint4*)&kbase[(size_t)(kt + r) * QKV_COLS + s * 8];
    }
    const unsigned short* vp = &vbase[(size_t)(kt + 2 * rp) * QKV_COLS + seg * 16];
    v0a = *(const ushort8_t*)vp;
    v0b = *(const ushort8_t*)(vp + 8);
    v1a = *(const ushort8_t*)(vp + QKV_COLS);
    v1b = *(const ushort8_t*)(vp + QKV_COLS + 8);
  };

  for (int half = 0; half < 2; ++half) {
    const int qt = (half == 0) ? (int)blockIdx.x : 31 - (int)blockIdx.x;
    const int q0 = qt * 64;
    const int qg = q0 + wq * 32 + l31;

    bf16x8 aq[8];
    #pragma unroll
    for (int ch = 0; ch < 8; ++ch)
      aq[ch] = ld8(&qbase[(size_t)qg * QKV_COLS + ch * 16 + lh * 8]);

    f32x16 o[4];
    #pragma unroll
    for (int dt = 0; dt < 4; ++dt) o[dt] = (f32x16)0.0f;
    float l_part = 0.0f;

    const int nkt = qt + 1;
    loadKV(0);
    for (int it = 0; it < nkt; ++it) {
      __syncthreads();                     // prior LDS reads done before overwrite
      #pragma unroll
      for (int p = 0; p < 4; ++p) {
        int ci = p * 256 + tid, r = ci >> 4, s = ci & 15;
        *(uint4*)&Ks[r * KSTR3 + s * 8] = kreg[p];
      }
      #pragma unroll
      for (int e = 0; e < 8; ++e) {
        *(unsigned int*)&Vs[(seg * 16 + e) * VSTR3 + 2 * rp] =
            (unsigned int)v0a[e] | ((unsigned int)v1a[e] << 16);
        *(unsigned int*)&Vs[(seg * 16 + 8 + e) * VSTR3 + 2 * rp] =
            (unsigned int)v0b[e] | ((unsigned int)v1b[e] << 16);
      }
      if (it + 1 < nkt) loadKV((it + 1) * KT3);   // prefetch next tile during compute
      __syncthreads();

      // S^T = K . Q^T  (32 key x 32 q per wave)
      f32x16 st = (f32x16)0.0f;
      #pragma unroll
      for (int ch = 0; ch < 8; ++ch) {
        bf16x8 kf = ld8(&Ks[(wk * 32 + l31) * KSTR3 + ch * 16 + lh * 8]);
        st = __builtin_amdgcn_mfma_f32_32x32x16_bf16(kf, aq[ch], st, 0, 0, 0);
      }
      const int kt = it * KT3;
      unsigned short* prow = &Ps[(wq * 32 + l31) * PSTR3 + wk * 32];
      #pragma unroll
      for (int g = 0; g < 4; ++g) {
        ushort4_t pk;
        #pragma unroll
        for (int e = 0; e < 4; ++e) {
          int r = g * 4 + e;
          int keyl = e + 8 * g + 4 * lh;
          int kg = kt + wk * 32 + keyl;
          float p = (kg <= qg) ? exp2f(st[r] * cf) : 0.0f;
          l_part += p;
          pk[e] = f2bf(p);
        }
        *(ushort4_t*)&prow[g * 8 + 4 * lh] = pk;
      }
      bf16x8 pf[2];
      #pragma unroll
      for (int kc = 0; kc < 2; ++kc) {
        uint2 pa = *(const uint2*)&Ps[(wq * 32 + l31) * PSTR3 + wk * 32 + kc * 16 + lh * 8];
        uint2 pb = *(const uint2*)&Ps[(wq * 32 + l31) * PSTR3 + wk * 32 + kc * 16 + lh * 8 + 4];
        union { uint4 u; bf16x8 v; } cvt;
        cvt.u.x = pa.x; cvt.u.y = pa.y; cvt.u.z = pb.x; cvt.u.w = pb.y;
        pf[kc] = cvt.v;
      }
      #pragma unroll
      for (int dt = 0; dt < 4; ++dt) {
        #pragma unroll
        for (int kc = 0; kc < 2; ++kc) {
          bf16x8 vf = ld8(&Vs[(dt * 32 + l31) * VSTR3 + wk * 32 + kc * 16 + lh * 8]);
          o[dt] = __builtin_amdgcn_mfma_f32_32x32x16_bf16(pf[kc], vf, o[dt], 0, 0, 0);
        }
      }
    }

    // ---- finalize: cross-wk O reduction + normalize + store ----
    float lv = l_part + __shfl_xor(l_part, 32, 64);
    __syncthreads();
    if (lane < 32) lred[wk * 64 + wq * 32 + lane] = lv;
    if (wk == 1) {
      #pragma unroll
      for (int dt = 0; dt < 4; ++dt)
        #pragma unroll
        for (int s = 0; s < 4; ++s) {
          f32x4 seg4 = {o[dt][s * 4 + 0], o[dt][s * 4 + 1], o[dt][s * 4 + 2], o[dt][s * 4 + 3]};
          *(f32x4*)&Os[(size_t)(wq * 64 + lane) * 68 + dt * 16 + s * 4] = seg4;
        }
    }
    __syncthreads();
    if (wk == 0) {
      float invr[16];
      #pragma unroll
      for (int r = 0; r < 16; ++r) {
        int ql = wq * 32 + (r & 3) + 8 * (r >> 2) + 4 * lh;
        invr[r] = 1.0f / (lred[ql] + lred[64 + ql]);
      }
      #pragma unroll
      for (int dt = 0; dt < 4; ++dt) {
        f32x4 add[4];
        #pragma unroll
        for (int s = 0; s < 4; ++s)
          add[s] = *(const f32x4*)&Os[(size_t)(wq * 64 + lane) * 68 + dt * 16 + s * 4];
        #pragma unroll
        for (int r = 0; r < 16; ++r) {
          float val = (o[dt][r] + add[r >> 2][r & 3]) * invr[r];
          int qrow = q0 + wq * 32 + (r & 3) + 8 * (r >> 2) + 4 * lh;
          aout[(size_t)((size_t)b * T_SEQ + qrow) * INNER + h * HD + dt * 32 + l31] = f2bf(val);
        }
      }
    }
  }
}

extern "C" void kernel_launch(void* const* d_in, const int* in_sizes, int n_in,
                              void* d_out, int out_size, void* d_ws, size_t ws_size,
                              hipStream_t stream) {
  const void* x     = d_in[0];   // [4096][2048]  fp32 or bf16 (device-detected)
  const void* w_qkv = d_in[1];   // [2048][6144]
  const void* w_out = d_in[2];   // [2048][2048]
  float* out = (float*)d_out;    // [4096][2048] fp32

  int* flag = (int*)d_ws;
  unsigned short* qkvbuf  = (unsigned short*)((char*)d_ws + 256);          // BT*6144
  unsigned short* attnout = qkvbuf + (size_t)BT_ROWS * QKV_COLS;           // BT*2048
  unsigned short* wqkvT   = attnout + (size_t)BT_ROWS * INNER;             // 6144*2048
  unsigned short* woutT   = wqkvT + (size_t)QKV_COLS * DIMSZ;              // 2048*2048
  unsigned short* xb      = woutT + (size_t)DIMSZ * INNER;                 // BT*2048
  // rope tables overlay the attnout region (dead until flash; tables dead after QKV GEMM)
  float* costab = (float*)attnout;
  float* sintab = costab + T_SEQ * 64;

  detect_dtype<<<1, 256, 0, stream>>>((const unsigned short*)w_qkv, flag);
  convert_x<<<dim3((size_t)BT_ROWS * DIMSZ / 2048), 256, 0, stream>>>(x, xb, flag);
  transpose_any<<<dim3(QKV_COLS / 32, DIMSZ / 32), 256, 0, stream>>>(w_qkv, wqkvT, DIMSZ, QKV_COLS, flag);
  transpose_any<<<dim3(DIMSZ / 32, INNER / 32), 256, 0, stream>>>(w_out, woutT, INNER, DIMSZ, flag);
  rope_tables<<<dim3(T_SEQ * 64 / 256), 256, 0, stream>>>(costab, sintab);
  gemm_lds2<<<dim3(QKV_COLS / 128, BT_ROWS / 128), 256, 0, stream>>>(
      xb, wqkvT, qkvbuf, nullptr, BT_ROWS, QKV_COLS, DIMSZ, costab, sintab, 2 * INNER);
  flash_attn4<<<dim3(16, BATCH * NHEADS), 256, 0, stream>>>(qkvbuf, attnout);
  gemm_lds2<<<dim3(DIMSZ / 128, BT_ROWS / 128), 256, 0, stream>>>(
      attnout, woutT, nullptr, out, BT_ROWS, DIMSZ, INNER, nullptr, nullptr, 0);
}

// Round 7
// 434.245 us; speedup vs baseline: 1.0443x; 1.0443x over previous
//
#include <hip/hip_runtime.h>
#include <hip/hip_bf16.h>
#include <math.h>

typedef __bf16 bf16x8 __attribute__((ext_vector_type(8)));
typedef float f32x4 __attribute__((ext_vector_type(4)));
typedef float f32x16 __attribute__((ext_vector_type(16)));
typedef unsigned short ushort8_t __attribute__((ext_vector_type(8)));
typedef unsigned short ushort4_t __attribute__((ext_vector_type(4)));

#define DIMSZ 2048
#define NHEADS 16
#define HD 128
#define INNER 2048
#define T_SEQ 2048
#define BATCH 2
#define BT_ROWS (BATCH * T_SEQ)      // 4096
#define QKV_COLS (3 * INNER)         // 6144

__device__ __forceinline__ float bf2f(unsigned short u) {
  union { unsigned int ui; float f; } v; v.ui = ((unsigned int)u) << 16; return v.f;
}
__device__ __forceinline__ unsigned short f2bf(float f) {
  union { float f; unsigned int ui; } v; v.f = f;
  unsigned int u = v.ui;
  return (unsigned short)((u + 0x7FFFu + ((u >> 16) & 1u)) >> 16);  // RNE
}
__device__ __forceinline__ bf16x8 ld8(const unsigned short* p) {
  return *(const bf16x8*)p;
}
// async global->LDS, 16B/lane. LDS dest = wave-uniform base + lane*16.
__device__ __forceinline__ void gl16(const unsigned short* g, unsigned short* l) {
  __builtin_amdgcn_global_load_lds(
      (const __attribute__((address_space(1))) unsigned int*)g,
      (__attribute__((address_space(3))) unsigned int*)l, 16, 0, 0);
}

// -------- dtype probe --------
__global__ void detect_dtype(const unsigned short* __restrict__ w, int* __restrict__ flag) {
  __shared__ int sh;
  if (threadIdx.x == 0) sh = 0;
  __syncthreads();
  int hit = 0;
  for (int i = threadIdx.x; i < 8192; i += 256) {
    unsigned int e = (w[i] >> 7) & 0xFF;
    if (e >= 0x7F) hit = 1;                       // |v| >= 1.0 impossible for bf16 weights
  }
  if (hit) atomicOr(&sh, 1);
  __syncthreads();
  if (threadIdx.x == 0) *flag = sh;               // 1 => inputs are fp32
}

// -------- x convert: fp32 (or bf16 passthrough) -> bf16 --------
__global__ void convert_x(const void* __restrict__ in, unsigned short* __restrict__ out,
                          const int* __restrict__ flag) {
  const bool f32 = (*flag != 0);
  size_t i = ((size_t)blockIdx.x * 256 + threadIdx.x) * 8;
  if (f32) {
    const float* inf = (const float*)in;
    float4 u0 = *(const float4*)&inf[i];
    float4 u1 = *(const float4*)&inf[i + 4];
    ushort8_t t;
    t[0] = f2bf(u0.x); t[1] = f2bf(u0.y); t[2] = f2bf(u0.z); t[3] = f2bf(u0.w);
    t[4] = f2bf(u1.x); t[5] = f2bf(u1.y); t[6] = f2bf(u1.z); t[7] = f2bf(u1.w);
    *(ushort8_t*)&out[i] = t;
  } else {
    *(uint4*)&out[i] = *(const uint4*)&((const unsigned short*)in)[i];
  }
}

// -------- weight transpose (+ optional fp32->bf16) --------
__global__ void transpose_any(const void* __restrict__ in, unsigned short* __restrict__ out,
                              int R, int C, const int* __restrict__ flag) {
  const bool f32 = (*flag != 0);
  __shared__ unsigned short tile[32][33];
  int c0 = blockIdx.x * 32, r0 = blockIdx.y * 32;
  int tx = threadIdx.x & 31, ty = threadIdx.x >> 5;
  if (f32) {
    const float* inf = (const float*)in;
    #pragma unroll
    for (int i = 0; i < 4; ++i)
      tile[ty + i * 8][tx] = f2bf(inf[(size_t)(r0 + ty + i * 8) * C + c0 + tx]);
  } else {
    const unsigned short* inu = (const unsigned short*)in;
    #pragma unroll
    for (int i = 0; i < 4; ++i)
      tile[ty + i * 8][tx] = inu[(size_t)(r0 + ty + i * 8) * C + c0 + tx];
  }
  __syncthreads();
  #pragma unroll
  for (int i = 0; i < 4; ++i)
    out[(size_t)(c0 + ty + i * 8) * R + r0 + tx] = tile[tx][ty + i * 8];
}

// -------- rope tables: cos/sin [2048][64] fp32 --------
__global__ void rope_tables(float* __restrict__ ct, float* __restrict__ st) {
  int i = blockIdx.x * 256 + threadIdx.x;     // 131072
  int t = i >> 6, j = i & 63;
  float inv_freq = exp2f(-(float)j * 0.20762050593046017f);  // log2(10000)/64
  float ang = (float)t * inv_freq;
  ct[i] = cosf(ang);
  st[i] = sinf(ang);
}

// ------------- GEMM v2: BK=64, XOR-swizzled LDS segments, optional fused RoPE epilogue -------------
#define GBK 64
__global__ __launch_bounds__(256) void gemm_lds2(const unsigned short* __restrict__ A,
                                                 const unsigned short* __restrict__ Bt,
                                                 unsigned short* __restrict__ Cb,
                                                 float* __restrict__ Cf,
                                                 int M, int N, int K,
                                                 const float* __restrict__ costab,
                                                 const float* __restrict__ sintab,
                                                 int rope_limit) {
  __shared__ union {
    unsigned short stage[2][128 * GBK];   // As, Bs (16 KB each)
    unsigned short tile[128 * 136];       // rope epilogue staging (34816 B)
  } sm;
  unsigned short* As = sm.stage[0];
  unsigned short* Bs = sm.stage[1];
  const int tid = threadIdx.x;
  const int m0 = blockIdx.y * 128, n0 = blockIdx.x * 128;
  const int w = tid >> 6, L = tid & 63, c = L & 15, quad = L >> 4;
  const int wm = (w & 1) * 64, wn = (w >> 1) * 64;
  f32x4 acc[4][4];
  #pragma unroll
  for (int i = 0; i < 4; ++i)
    #pragma unroll
    for (int j = 0; j < 4; ++j) acc[i][j] = (f32x4)0.0f;

  for (int k0 = 0; k0 < K; k0 += GBK) {
    #pragma unroll
    for (int p = 0; p < 4; ++p) {
      int ci = p * 256 + w * 64 + L;      // slot 0..1023
      int r = ci >> 3, s = ci & 7;
      int sl = s ^ (r & 7);               // swizzle via global source permutation
      gl16(&A[(size_t)(m0 + r) * K + k0 + sl * 8], &As[(p * 256 + w * 64) * 8]);
      gl16(&Bt[(size_t)(n0 + r) * K + k0 + sl * 8], &Bs[(p * 256 + w * 64) * 8]);
    }
    __syncthreads();
    #pragma unroll
    for (int sub = 0; sub < 2; ++sub) {
      bf16x8 af[4], bfr[4];
      #pragma unroll
      for (int i = 0; i < 4; ++i)
        af[i] = ld8(&As[(wm + i * 16 + c) * GBK + (((sub * 4 + quad) ^ (c & 7)) * 8)]);
      #pragma unroll
      for (int j = 0; j < 4; ++j)
        bfr[j] = ld8(&Bs[(wn + j * 16 + c) * GBK + (((sub * 4 + quad) ^ (c & 7)) * 8)]);
      #pragma unroll
      for (int i = 0; i < 4; ++i)
        #pragma unroll
        for (int j = 0; j < 4; ++j)
          acc[i][j] = __builtin_amdgcn_mfma_f32_16x16x32_bf16(af[i], bfr[j], acc[i][j], 0, 0, 0);
    }
    __syncthreads();
  }
  // C/D layout: col = lane&15, row = quad*4 + reg
  if (Cf) {
    #pragma unroll
    for (int i = 0; i < 4; ++i)
      #pragma unroll
      for (int j = 0; j < 4; ++j)
        #pragma unroll
        for (int r = 0; r < 4; ++r)
          Cf[(size_t)(m0 + wm + i * 16 + quad * 4 + r) * N + n0 + wn + j * 16 + c] = acc[i][j][r];
  } else if (n0 < rope_limit) {
    // fused RoPE: this block covers one head's 128 dims of q or k.
    #pragma unroll
    for (int i = 0; i < 4; ++i)
      #pragma unroll
      for (int j = 0; j < 4; ++j)
        #pragma unroll
        for (int r = 0; r < 4; ++r)
          sm.tile[(wm + i * 16 + quad * 4 + r) * 136 + wn + j * 16 + c] = f2bf(acc[i][j][r]);
    __syncthreads();
    int rbase = w * 8 + (L >> 3);          // 0..31
    int cb = (L & 7) * 8;                  // 0..56
    #pragma unroll
    for (int p = 0; p < 4; ++p) {
      int row = rbase + p * 32;
      int tp = (m0 + row) & (T_SEQ - 1);
      const float* cr = &costab[tp * 64 + cb];
      const float* sr = &sintab[tp * 64 + cb];
      float4 c0v = *(const float4*)cr, c1v = *(const float4*)(cr + 4);
      float4 s0v = *(const float4*)sr, s1v = *(const float4*)(sr + 4);
      float cv[8] = {c0v.x, c0v.y, c0v.z, c0v.w, c1v.x, c1v.y, c1v.z, c1v.w};
      float sv[8] = {s0v.x, s0v.y, s0v.z, s0v.w, s1v.x, s1v.y, s1v.z, s1v.w};
      bf16x8 x1 = ld8(&sm.tile[row * 136 + cb]);
      bf16x8 x2 = ld8(&sm.tile[row * 136 + cb + 64]);
      ushort8_t o1, o2;
      #pragma unroll
      for (int e = 0; e < 8; ++e) {
        float a = (float)x1[e], bq = (float)x2[e];
        o1[e] = f2bf(a * cv[e] - bq * sv[e]);
        o2[e] = f2bf(bq * cv[e] + a * sv[e]);
      }
      *(ushort8_t*)&Cb[(size_t)(m0 + row) * N + n0 + cb] = o1;
      *(ushort8_t*)&Cb[(size_t)(m0 + row) * N + n0 + cb + 64] = o2;
    }
    __syncthreads();
  } else {
    #pragma unroll
    for (int i = 0; i < 4; ++i)
      #pragma unroll
      for (int j = 0; j < 4; ++j)
        #pragma unroll
        for (int r = 0; r < 4; ++r)
          Cb[(size_t)(m0 + wm + i * 16 + quad * 4 + r) * N + n0 + wn + j * 16 + c] =
              f2bf(acc[i][j][r]);
  }
}

// ---------------- causal flash attention v5: XCD-pinned grid, one q-tile per block ----------------
// grid (32 bh, 32 y): bh = blockIdx.x => flat%8 = bh%8 pins all blocks of one (b,h) to one XCD
// (KV prefix stays L2-resident: 4 bh/XCD x 1 MB = 4 MB = L2). qt = 31-y: longest blocks first.
#define KT3 64
#define KSTR3 136
#define VSTR3 72
#define PSTR3 68
#define SM_VS (64 * KSTR3 * 2)             // 17408
#define SM_PS (SM_VS + 128 * VSTR3 * 2)    // 35840
#define SM_LR (SM_PS + 64 * PSTR3 * 2)     // 44544
#define SM_TOT (SM_LR + 2 * 64 * 4)        // 45056
__global__ __launch_bounds__(256, 2) void flash_attn5(const unsigned short* __restrict__ qkv,
                                                      unsigned short* __restrict__ aout) {
  __shared__ char smem[SM_TOT];
  unsigned short* Ks = (unsigned short*)smem;              // [64 key][KSTR3]
  unsigned short* Vs = (unsigned short*)(smem + SM_VS);    // [128 d][VSTR3] (transposed)
  unsigned short* Ps = (unsigned short*)(smem + SM_PS);    // [64 q][PSTR3]
  float* lred = (float*)(smem + SM_LR);                    // [2 wk][64 q]
  float* Os = (float*)smem;                                // overlay: [2 wq][64 lane][68]

  const int tid = threadIdx.x, wave = tid >> 6, lane = tid & 63;
  const int wq = wave & 1, wk = wave >> 1;
  const int l31 = lane & 31, lh = lane >> 5;
  const int bh = blockIdx.x, b = bh >> 4, h = bh & 15;
  const int qt = 31 - (int)blockIdx.y;
  const unsigned short* qbase = qkv + (size_t)b * T_SEQ * QKV_COLS + h * HD;
  const unsigned short* kbase = qbase + INNER;
  const unsigned short* vbase = qbase + 2 * INNER;
  const float cf = 0.12751743f;            // (1/sqrt(128)) * log2(e)
  const int rp = tid & 31, seg = tid >> 5;

  uint4 kreg[4];
  ushort8_t v0a, v0b, v1a, v1b;
  auto loadKV = [&](int kt) {
    #pragma unroll
    for (int p = 0; p < 4; ++p) {
      int ci = p * 256 + tid, r = ci >> 4, s = ci & 15;
      kreg[p] = *(const uint4*)&kbase[(size_t)(kt + r) * QKV_COLS + s * 8];
    }
    const unsigned short* vp = &vbase[(size_t)(kt + 2 * rp) * QKV_COLS + seg * 16];
    v0a = *(const ushort8_t*)vp;
    v0b = *(const ushort8_t*)(vp + 8);
    v1a = *(const ushort8_t*)(vp + QKV_COLS);
    v1b = *(const ushort8_t*)(vp + QKV_COLS + 8);
  };

  const int q0 = qt * 64;
  const int qg = q0 + wq * 32 + l31;

  bf16x8 aq[8];
  #pragma unroll
  for (int ch = 0; ch < 8; ++ch)
    aq[ch] = ld8(&qbase[(size_t)qg * QKV_COLS + ch * 16 + lh * 8]);

  f32x16 o[4];
  #pragma unroll
  for (int dt = 0; dt < 4; ++dt) o[dt] = (f32x16)0.0f;
  float l_part = 0.0f;

  const int nkt = qt + 1;
  loadKV(0);
  for (int it = 0; it < nkt; ++it) {
    __syncthreads();                     // prior LDS reads done before overwrite
    #pragma unroll
    for (int p = 0; p < 4; ++p) {
      int ci = p * 256 + tid, r = ci >> 4, s = ci & 15;
      *(uint4*)&Ks[r * KSTR3 + s * 8] = kreg[p];
    }
    #pragma unroll
    for (int e = 0; e < 8; ++e) {
      *(unsigned int*)&Vs[(seg * 16 + e) * VSTR3 + 2 * rp] =
          (unsigned int)v0a[e] | ((unsigned int)v1a[e] << 16);
      *(unsigned int*)&Vs[(seg * 16 + 8 + e) * VSTR3 + 2 * rp] =
          (unsigned int)v0b[e] | ((unsigned int)v1b[e] << 16);
    }
    if (it + 1 < nkt) loadKV((it + 1) * KT3);   // prefetch next tile during compute
    __syncthreads();

    // S^T = K . Q^T  (32 key x 32 q per wave)
    f32x16 st = (f32x16)0.0f;
    #pragma unroll
    for (int ch = 0; ch < 8; ++ch) {
      bf16x8 kf = ld8(&Ks[(wk * 32 + l31) * KSTR3 + ch * 16 + lh * 8]);
      st = __builtin_amdgcn_mfma_f32_32x32x16_bf16(kf, aq[ch], st, 0, 0, 0);
    }
    const int kt = it * KT3;
    unsigned short* prow = &Ps[(wq * 32 + l31) * PSTR3 + wk * 32];
    #pragma unroll
    for (int g = 0; g < 4; ++g) {
      ushort4_t pk;
      #pragma unroll
      for (int e = 0; e < 4; ++e) {
        int r = g * 4 + e;
        int keyl = e + 8 * g + 4 * lh;
        int kg = kt + wk * 32 + keyl;
        float p = (kg <= qg) ? exp2f(st[r] * cf) : 0.0f;
        l_part += p;
        pk[e] = f2bf(p);
      }
      *(ushort4_t*)&prow[g * 8 + 4 * lh] = pk;
    }
    bf16x8 pf[2];
    #pragma unroll
    for (int kc = 0; kc < 2; ++kc) {
      uint2 pa = *(const uint2*)&Ps[(wq * 32 + l31) * PSTR3 + wk * 32 + kc * 16 + lh * 8];
      uint2 pb = *(const uint2*)&Ps[(wq * 32 + l31) * PSTR3 + wk * 32 + kc * 16 + lh * 8 + 4];
      union { uint4 u; bf16x8 v; } cvt;
      cvt.u.x = pa.x; cvt.u.y = pa.y; cvt.u.z = pb.x; cvt.u.w = pb.y;
      pf[kc] = cvt.v;
    }
    #pragma unroll
    for (int dt = 0; dt < 4; ++dt) {
      #pragma unroll
      for (int kc = 0; kc < 2; ++kc) {
        bf16x8 vf = ld8(&Vs[(dt * 32 + l31) * VSTR3 + wk * 32 + kc * 16 + lh * 8]);
        o[dt] = __builtin_amdgcn_mfma_f32_32x32x16_bf16(pf[kc], vf, o[dt], 0, 0, 0);
      }
    }
  }

  // ---- finalize: cross-wk O reduction + normalize + store ----
  float lv = l_part + __shfl_xor(l_part, 32, 64);
  __syncthreads();
  if (lane < 32) lred[wk * 64 + wq * 32 + lane] = lv;
  if (wk == 1) {
    #pragma unroll
    for (int dt = 0; dt < 4; ++dt)
      #pragma unroll
      for (int s = 0; s < 4; ++s) {
        f32x4 seg4 = {o[dt][s * 4 + 0], o[dt][s * 4 + 1], o[dt][s * 4 + 2], o[dt][s * 4 + 3]};
        *(f32x4*)&Os[(size_t)(wq * 64 + lane) * 68 + dt * 16 + s * 4] = seg4;
      }
  }
  __syncthreads();
  if (wk == 0) {
    float invr[16];
    #pragma unroll
    for (int r = 0; r < 16; ++r) {
      int ql = wq * 32 + (r & 3) + 8 * (r >> 2) + 4 * lh;
      invr[r] = 1.0f / (lred[ql] + lred[64 + ql]);
    }
    #pragma unroll
    for (int dt = 0; dt < 4; ++dt) {
      f32x4 add[4];
      #pragma unroll
      for (int s = 0; s < 4; ++s)
        add[s] = *(const f32x4*)&Os[(size_t)(wq * 64 + lane) * 68 + dt * 16 + s * 4];
      #pragma unroll
      for (int r = 0; r < 16; ++r) {
        float val = (o[dt][r] + add[r >> 2][r & 3]) * invr[r];
        int qrow = q0 + wq * 32 + (r & 3) + 8 * (r >> 2) + 4 * lh;
        aout[(size_t)((size_t)b * T_SEQ + qrow) * INNER + h * HD + dt * 32 + l31] = f2bf(val);
      }
    }
  }
}

extern "C" void kernel_launch(void* const* d_in, const int* in_sizes, int n_in,
                              void* d_out, int out_size, void* d_ws, size_t ws_size,
                              hipStream_t stream) {
  const void* x     = d_in[0];   // [4096][2048]  fp32 or bf16 (device-detected)
  const void* w_qkv = d_in[1];   // [2048][6144]
  const void* w_out = d_in[2];   // [2048][2048]
  float* out = (float*)d_out;    // [4096][2048] fp32

  int* flag = (int*)d_ws;
  unsigned short* qkvbuf  = (unsigned short*)((char*)d_ws + 256);          // BT*6144
  unsigned short* attnout = qkvbuf + (size_t)BT_ROWS * QKV_COLS;           // BT*2048
  unsigned short* wqkvT   = attnout + (size_t)BT_ROWS * INNER;             // 6144*2048
  unsigned short* woutT   = wqkvT + (size_t)QKV_COLS * DIMSZ;              // 2048*2048
  unsigned short* xb      = woutT + (size_t)DIMSZ * INNER;                 // BT*2048
  float* costab = (float*)attnout;   // overlay (dead until flash; tables dead after QKV GEMM)
  float* sintab = costab + T_SEQ * 64;

  detect_dtype<<<1, 256, 0, stream>>>((const unsigned short*)w_qkv, flag);
  convert_x<<<dim3((size_t)BT_ROWS * DIMSZ / 2048), 256, 0, stream>>>(x, xb, flag);
  transpose_any<<<dim3(QKV_COLS / 32, DIMSZ / 32), 256, 0, stream>>>(w_qkv, wqkvT, DIMSZ, QKV_COLS, flag);
  transpose_any<<<dim3(DIMSZ / 32, INNER / 32), 256, 0, stream>>>(w_out, woutT, INNER, DIMSZ, flag);
  rope_tables<<<dim3(T_SEQ * 64 / 256), 256, 0, stream>>>(costab, sintab);
  gemm_lds2<<<dim3(QKV_COLS / 128, BT_ROWS / 128), 256, 0, stream>>>(
      xb, wqkvT, qkvbuf, nullptr, BT_ROWS, QKV_COLS, DIMSZ, costab, sintab, 2 * INNER);
  flash_attn5<<<dim3(BATCH * NHEADS, 32), 256, 0, stream>>>(qkvbuf, attnout);
  gemm_lds2<<<dim3(DIMSZ / 128, BT_ROWS / 128), 256, 0, stream>>>(
      attnout, woutT, nullptr, out, BT_ROWS, DIMSZ, INNER, nullptr, nullptr, 0);
}